// Round 9
// baseline (277.827 us; speedup 1.0000x reference)
//
#include <hip/hip_runtime.h>
#include <hip/hip_bf16.h>

// Problem constants
#define U     1024
#define SLEN  2048
#define HEADS 16
#define DK    64
#define MTOT  4096   // B*S
#define MU    (MTOT * U)   // 4M elements
#define UU    (U * U)      // 1M elements

// 1/sqrt(64) * log2(e): folded into Q at the qkv epilogue -> flash softmax
// runs entirely in the exp2 domain with zero per-score scaling.
#define QSCALE2 0.18033688f

typedef unsigned short u16;
typedef short bf16x8 __attribute__((ext_vector_type(8)));
typedef u16 u16x4 __attribute__((ext_vector_type(4)));
typedef float f32x4 __attribute__((ext_vector_type(4)));

__device__ __forceinline__ u16 f2bf(float x) {
  union { float f; unsigned int u; } v; v.f = x;
  unsigned int r = v.u + 0x7fffu + ((v.u >> 16) & 1u);
  return (u16)(r >> 16);
}
// truncating bf16 (1 VALU op); used for P weights only (p>=0, err <= 2^-8 rel)
__device__ __forceinline__ u16 f2bf_rz(float x) {
  return (u16)(__builtin_bit_cast(unsigned int, x) >> 16);
}

#if __has_builtin(__builtin_amdgcn_exp2f)
__device__ __forceinline__ float exp2_fast(float x) { return __builtin_amdgcn_exp2f(x); }
#else
__device__ __forceinline__ float exp2_fast(float x) { return __expf(x * 0.6931472f); }
#endif

// async global->LDS, 16B per lane. LDS dest is wave-uniform base + lane*16.
__device__ __forceinline__ void async16(const u16* g, u16* lds) {
  __builtin_amdgcn_global_load_lds((const __attribute__((address_space(1))) void*)g,
                                   (__attribute__((address_space(3))) void*)lds,
                                   16, 0, 0);
}

// ---- DPP 16-lane sum (VALU-rate); used ONCE at flash epilogue ----
#define DPP_F(x, ctrl) __builtin_bit_cast(float, \
    __builtin_amdgcn_update_dpp(0, __builtin_bit_cast(int, (x)), (ctrl), 0xF, 0xF, true))

__device__ __forceinline__ float rsum16(float x) {
  x += DPP_F(x, 0xB1);
  x += DPP_F(x, 0x4E);
  x += DPP_F(x, 0x141);
  x += DPP_F(x, 0x140);
  return x;
}

// ---------------- fp32 -> bf16 conversion prepass ----------------
__global__ __launch_bounds__(256) void convert_kernel(
    const float* __restrict__ q, const float* __restrict__ k, const float* __restrict__ v,
    const float* __restrict__ wq, const float* __restrict__ wk,
    const float* __restrict__ wv, const float* __restrict__ wo,
    u16* __restrict__ cq, u16* __restrict__ ck, u16* __restrict__ cv,
    u16* __restrict__ cwq, u16* __restrict__ cwk, u16* __restrict__ cwv,
    u16* __restrict__ cwo) {
  const int t = blockIdx.y;
  const float* src = (t == 0) ? q : (t == 1) ? k : (t == 2) ? v
                   : (t == 3) ? wq : (t == 4) ? wk : (t == 5) ? wv : wo;
  u16* dst = (t == 0) ? cq : (t == 1) ? ck : (t == 2) ? cv
           : (t == 3) ? cwq : (t == 4) ? cwk : (t == 5) ? cwv : cwo;
  const int n4 = ((t < 3) ? MU : UU) >> 2;
  const int stride = gridDim.x * blockDim.x;
  for (int i = blockIdx.x * blockDim.x + threadIdx.x; i < n4; i += stride) {
    float4 f = ((const float4*)src)[i];
    u16x4 o = {f2bf(f.x), f2bf(f.y), f2bf(f.z), f2bf(f.w)};
    ((u16x4*)dst)[i] = o;
  }
}

// ---------------- GEMM core: C[128x128] += X[128xK] * W[128xK]^T, K=1024 ----
// R9: TWO-slot LDS (32 KB) -> 5 blocks/CU resident (was 3 at 48 KB). R8's
// post-mortem: nothing is saturated (LDS pipe ~34%, MFMA 21%, HBM 18%) --
// qkv is LATENCY-bound at ~6 waves/CU avg. More resident blocks = more
// inter-block overlap of the barrier-lockstep critical path.
// Schedule per iter t: vmcnt(0) [drains tile t's 4 loads, issued one full
// iter ago -> ~0 stall] -> s_barrier -> stage tile t+1 into slot^1 ->
// ds_read slot + 16 MFMA.
// Race-freedom (2 slots, 1 barrier/iter): slot^1 holds tile t-1, whose 8
// ds_reads all feed MFMAs issued BEFORE barrier_t in every wave's program
// order (lgkmcnt retires them pre-MFMA); stage writes are issued strictly
// post-barrier_t -> no wave can see an overwrite before its reads retired.
__device__ __forceinline__ void stage_tile(const u16* __restrict__ src, int kt,
                                           u16* lds, int tid) {
#pragma unroll
  for (int c = 0; c < 2; ++c) {
    int f = c * 256 + tid;               // chunk index 0..511
    int row = f >> 2;
    int qs = f & 3;
    int q = qs ^ ((row >> 1) & 3);       // global 16B-chunk within the row
    const u16* g = src + (size_t)row * U + kt + q * 8;
    u16* l = lds + (size_t)(f & ~63) * 8;  // wave-uniform base (lane bits cleared)
    async16(g, l);
  }
}

__device__ __forceinline__ bf16x8 read_frag(const u16* lds, int lrow, int quad) {
  int qs = quad ^ ((lrow >> 1) & 3);
  return *(const bf16x8*)(lds + (size_t)(lrow * 4 + qs) * 8);
}

__device__ __forceinline__ void gemm128(const u16* __restrict__ X,
                                        const u16* __restrict__ W,
                                        int m0, int n0, int tid,
                                        u16* lds,            // 2 x (4096 A + 4096 B) u16
                                        f32x4 acc[4][4]) {
  const int l = tid & 63, w = tid >> 6;
  const int quad = l >> 4, l15 = l & 15;
  const int wm = w & 1, wn = w >> 1;
  const u16* Xb = X + (size_t)m0 * U;
  const u16* Wb = W + (size_t)n0 * U;

  // prologue: stage K-tile 0 into slot 0 (4 loads/thread in flight)
  stage_tile(Xb, 0, lds, tid);
  stage_tile(Wb, 0, lds + 4096, tid);

  for (int kt = 0; kt < U; kt += 32) {
    const int cur = (kt >> 5) & 1;
    __builtin_amdgcn_sched_barrier(0);
    asm volatile("s_waitcnt vmcnt(0)" ::: "memory");  // tile t's 4 loads landed
    __builtin_amdgcn_sched_barrier(0);
    __builtin_amdgcn_s_barrier();        // all waves: tile t ready; t-1 reads retired
    __builtin_amdgcn_sched_barrier(0);
    if (kt + 32 < U) {                   // stage t+1 into the slot freed above
      stage_tile(Xb, kt + 32, lds + (cur ^ 1) * 8192, tid);
      stage_tile(Wb, kt + 32, lds + (cur ^ 1) * 8192 + 4096, tid);
    }
    __builtin_amdgcn_sched_barrier(0);

    const u16* la = lds + cur * 8192;
    const u16* lb = la + 4096;
    bf16x8 af[4], bfm[4];
#pragma unroll
    for (int i = 0; i < 4; ++i) af[i] = read_frag(la, wm * 64 + i * 16 + l15, quad);
#pragma unroll
    for (int t = 0; t < 4; ++t) bfm[t] = read_frag(lb, wn * 64 + t * 16 + l15, quad);
#pragma unroll
    for (int i = 0; i < 4; ++i)
#pragma unroll
      for (int t = 0; t < 4; ++t)
        acc[i][t] = __builtin_amdgcn_mfma_f32_16x16x32_bf16(af[i], bfm[t], acc[i][t], 0, 0, 0);
  }
}

// XCD-aware remap for an 8(x) x 32(y) grid: hardware XCD = flat id % 8.
// Map XCD k -> y-panels [4k, 4k+4) x all 8 x-panels, so each X row-panel is
// fetched by exactly ONE XCD's L2 (was 8). Per-XCD working set: 4 X panels
// (1 MB) + full W (2 MB) = 3 MB < 4 MB L2.
__device__ __forceinline__ void xcd_remap(int* m0, int* n0) {
  const int id = blockIdx.x + (blockIdx.y << 3);   // 0..255
  const int k = id & 7, j = id >> 3;               // k = hw XCD
  const int xp = j >> 2;                           // 0..7
  const int yp = (k << 2) | (j & 3);               // 0..31
  *m0 = yp * 128;
  *n0 = xp * 128;
}

// ---------------- QKV projection, fused over z = {q,k,v} ----------------
__global__ __launch_bounds__(256, 5) void qkv_gemm(
    const u16* __restrict__ q_in, const u16* __restrict__ k_in, const u16* __restrict__ v_in,
    const u16* __restrict__ Wq, const u16* __restrict__ Wk, const u16* __restrict__ Wv,
    const float* __restrict__ bq, const float* __restrict__ bk, const float* __restrict__ bv,
    u16* __restrict__ q_ws, u16* __restrict__ k_ws, u16* __restrict__ v_ws) {
  __shared__ __align__(16) u16 lds2[2 * 8192];     // 32 KB -> 5 blocks/CU
  const int z = blockIdx.z;
  const u16* X = (z == 0) ? q_in : (z == 1) ? k_in : v_in;
  const u16* W = (z == 0) ? Wq : (z == 1) ? Wk : Wv;
  const float* bias = (z == 0) ? bq : (z == 1) ? bk : bv;
  int m0, n0;
  xcd_remap(&m0, &n0);
  const int tid = threadIdx.x;
  f32x4 acc[4][4];
#pragma unroll
  for (int i = 0; i < 4; ++i)
#pragma unroll
    for (int t = 0; t < 4; ++t) acc[i][t] = (f32x4){0.f, 0.f, 0.f, 0.f};
  gemm128(X, W, m0, n0, tid, lds2, acc);

  const int l = tid & 63, w = tid >> 6;
  const int quad = l >> 4, l15 = l & 15;
  const int wm = w & 1, wn = w >> 1;
  const float osc = (z == 0) ? QSCALE2 : 1.0f;  // fold softmax scale into Q
#pragma unroll
  for (int t = 0; t < 4; ++t) {
    const int n = n0 + wn * 64 + t * 16 + l15;
    const float bb = bias[n];
    const int h = n >> 6, d = n & 63;
#pragma unroll
    for (int i = 0; i < 4; ++i) {
#pragma unroll
      for (int r = 0; r < 4; ++r) {
        const int m = m0 + wm * 64 + i * 16 + quad * 4 + r;
        const int b = m >> 11, s = m & (SLEN - 1);
        const int bh = b * HEADS + h;
        const u16 ov = f2bf((acc[i][t][r] + bb) * osc);
        if (z == 0)      q_ws[((size_t)bh * SLEN + s) * DK + d] = ov;
        else if (z == 1) k_ws[((size_t)bh * SLEN + s) * DK + d] = ov;
        else             v_ws[((size_t)bh * DK + d) * SLEN + s] = ov;
      }
    }
  }
}

// ---------------- Flash attention (causal, LDS-staged K/V, 64 q-rows/block) ----
// R2-PROVEN config (measured-best flash ~37.6 us): 4 waves x 16 q-rows, QBLK=64,
// 1024 blocks. K/V tiles staged once per block via global_load_lds
// (double-buffered, chunk-XOR swizzled). Block id = (31-qblk)*32 + head:
// longest-first AND same-head blocks cluster on one XCD so KV stays in L2.
// [R5/R6 lesson: frag-reuse redesigns that cut waves/CU lose to latency.]
__global__ __launch_bounds__(256, 4) void flash_attn(const u16* __restrict__ q_ws,
                                                     const u16* __restrict__ k_ws,
                                                     const u16* __restrict__ v_ws,
                                                     u16* __restrict__ a_ws) {
  __shared__ __align__(16) u16 kbuf[2][4096];      // 64 keys x 64 dk, swizzled
  __shared__ __align__(16) u16 vbuf[2][4096];      // 64 d    x 64 keys, swizzled
  __shared__ __align__(16) u16 p_lds[4][16][72];   // per-wave P slab (pad 64->72)
  const int id = blockIdx.x;
  const int bh = id & 31;
  const int qblk = 31 - (id >> 5);     // longest first
  const int tid = threadIdx.x;
  const int w = tid >> 6, l = tid & 63;
  const int quad = l >> 4, l15 = l & 15;
  const int qrow = qblk * 64 + w * 16; // this wave's first q-row
  const int jn = qblk;                 // last (masked) key tile

  const u16* qb = q_ws + (size_t)bh * SLEN * DK;
  const u16* kb = k_ws + (size_t)bh * SLEN * DK;
  const u16* vb = v_ws + (size_t)bh * DK * SLEN;

  // Q A-frags: A[m=lane&15][k=quad*8+j]
  bf16x8 aq0 = *(const bf16x8*)(qb + (size_t)(qrow + l15) * DK + quad * 8);
  bf16x8 aq1 = *(const bf16x8*)(qb + (size_t)(qrow + l15) * DK + 32 + quad * 8);

  f32x4 o[4];
  float l_run[4];
#pragma unroll
  for (int t = 0; t < 4; ++t) o[t] = (f32x4){0.f, 0.f, 0.f, 0.f};
#pragma unroll
  for (int r = 0; r < 4; ++r) l_run[r] = 0.f;

  // ---- cooperative K/V tile staging: 512 chunks each, XOR-swizzled ----
  // chunk f: row=f>>3, slot qs=f&7 holds global col-chunk q = qs ^ (row&7).
  auto stage = [&](int j0, int b) {
#pragma unroll
    for (int c = 0; c < 2; ++c) {
      const int f = c * 256 + tid;
      const int row = f >> 3, qs = f & 7;
      const int q = qs ^ (row & 7);
      u16* kdst = kbuf[b] + (size_t)(f & ~63) * 8;   // wave-uniform base
      u16* vdst = vbuf[b] + (size_t)(f & ~63) * 8;
      async16(kb + (size_t)(j0 + row) * DK + q * 8, kdst);
      async16(vb + (size_t)row * SLEN + j0 + q * 8, vdst);
    }
  };

  stage(0, 0);
  __syncthreads();   // drains vmcnt -> tile 0 ready

  for (int jt = 0; jt <= jn; ++jt) {
    const int buf = jt & 1;
    if (jt < jn) stage((jt + 1) * 64, buf ^ 1);   // async prefetch, no VGPR cost
    const int j0 = jt * 64;
    const int swz = l15 & 7;                      // (t*16+l15)&7 == l15&7

    // ---- S = Q K^T (already exp2-scaled via Q); K-frags from LDS ----
    float sv[4][4];
#pragma unroll
    for (int t = 0; t < 4; ++t) {
      const u16* krow = kbuf[buf] + (size_t)(t * 16 + l15) * 64;
      bf16x8 kf0 = *(const bf16x8*)(krow + ((quad ^ swz) * 8));
      bf16x8 kf1 = *(const bf16x8*)(krow + (((quad + 4) ^ swz) * 8));
      f32x4 acc = (f32x4){0.f, 0.f, 0.f, 0.f};
      acc = __builtin_amdgcn_mfma_f32_16x16x32_bf16(aq0, kf0, acc, 0, 0, 0);
      acc = __builtin_amdgcn_mfma_f32_16x16x32_bf16(aq1, kf1, acc, 0, 0, 0);
#pragma unroll
      for (int r = 0; r < 4; ++r) sv[t][r] = acc[r];
    }
    if (jt == jn) {  // causal mask, block-uniform branch (per-lane predicate)
#pragma unroll
      for (int t = 0; t < 4; ++t) {
        const int col = j0 + t * 16 + l15;
#pragma unroll
        for (int r = 0; r < 4; ++r)
          if (col > qrow + quad * 4 + r) sv[t][r] = -1e30f;  // exp2 -> 0
      }
    }
    // ---- p = exp2(s); unnormalized; per-lane l partial ----
#pragma unroll
    for (int t = 0; t < 4; ++t) {
#pragma unroll
      for (int r = 0; r < 4; ++r) {
        const float p = exp2_fast(sv[t][r]);
        l_run[r] += p;
        p_lds[w][quad * 4 + r][t * 16 + l15] = f2bf_rz(p);  // C-layout -> LDS
      }
    }
    // wave-internal LDS ordering via lgkmcnt (per-wave slab, no barrier)
    bf16x8 pa0 = *(const bf16x8*)&p_lds[w][l15][quad * 8];
    bf16x8 pa1 = *(const bf16x8*)&p_lds[w][l15][32 + quad * 8];
#pragma unroll
    for (int t = 0; t < 4; ++t) {
      const u16* vrow = vbuf[buf] + (size_t)(t * 16 + l15) * 64;
      bf16x8 vf0 = *(const bf16x8*)(vrow + ((quad ^ swz) * 8));
      bf16x8 vf1 = *(const bf16x8*)(vrow + (((quad + 4) ^ swz) * 8));
      o[t] = __builtin_amdgcn_mfma_f32_16x16x32_bf16(pa0, vf0, o[t], 0, 0, 0);
      o[t] = __builtin_amdgcn_mfma_f32_16x16x32_bf16(pa1, vf1, o[t], 0, 0, 0);
    }
    __syncthreads();  // all waves done with buf; prefetch into buf^1 drained
  }
  // ---- epilogue: each wave normalizes & stores its own 16 rows ----
  const int b = bh >> 4, h = bh & 15;
  float inv[4];
#pragma unroll
  for (int r = 0; r < 4; ++r) inv[r] = 1.f / rsum16(l_run[r]);
#pragma unroll
  for (int r = 0; r < 4; ++r) {
    const int s = qrow + quad * 4 + r;
    u16* orow = a_ws + ((size_t)b * SLEN + s) * U + h * DK;
#pragma unroll
    for (int t = 0; t < 4; ++t)
      orow[t * 16 + l15] = f2bf(o[t][r] * inv[r]);
  }
}

// ---------------- output projection (fp32 output) ----------------
__global__ __launch_bounds__(256, 5) void oproj_gemm(const u16* __restrict__ A,
                                                     const u16* __restrict__ Wo,
                                                     const float* __restrict__ bo,
                                                     float* __restrict__ out) {
  __shared__ __align__(16) u16 lds2[2 * 8192];
  int m0, n0;
  xcd_remap(&m0, &n0);
  const int tid = threadIdx.x;
  f32x4 acc[4][4];
#pragma unroll
  for (int i = 0; i < 4; ++i)
#pragma unroll
    for (int t = 0; t < 4; ++t) acc[i][t] = (f32x4){0.f, 0.f, 0.f, 0.f};
  gemm128(A, Wo, m0, n0, tid, lds2, acc);

  const int l = tid & 63, w = tid >> 6;
  const int quad = l >> 4, l15 = l & 15;
  const int wm = w & 1, wn = w >> 1;
#pragma unroll
  for (int t = 0; t < 4; ++t) {
    const int n = n0 + wn * 64 + t * 16 + l15;
    const float bb = bo[n];
#pragma unroll
    for (int i = 0; i < 4; ++i) {
#pragma unroll
      for (int r = 0; r < 4; ++r) {
        const int m = m0 + wm * 64 + i * 16 + quad * 4 + r;
        out[(size_t)m * U + n] = acc[i][t][r] + bb;
      }
    }
  }
}

extern "C" void kernel_launch(void* const* d_in, const int* in_sizes, int n_in,
                              void* d_out, int out_size, void* d_ws, size_t ws_size,
                              hipStream_t stream) {
  (void)in_sizes; (void)n_in; (void)out_size; (void)ws_size;
  const float* query = (const float*)d_in[0];
  const float* key_  = (const float*)d_in[1];
  const float* value = (const float*)d_in[2];
  // d_in[3] = mask (tril causal; hardcoded in flash kernel)
  const float* Wq = (const float*)d_in[4];
  const float* bq = (const float*)d_in[5];
  const float* Wk = (const float*)d_in[6];
  const float* bk = (const float*)d_in[7];
  const float* Wv = (const float*)d_in[8];
  const float* bv = (const float*)d_in[9];
  const float* Wo = (const float*)d_in[10];
  const float* bo = (const float*)d_in[11];

  u16* ws = (u16*)d_ws;
  u16* cq  = ws;                 // 4M bf16 [B*S, U]
  u16* ck  = cq + MU;            // 4M
  u16* cv  = ck + MU;            // 4M
  u16* cwq = cv + MU;            // 1M bf16 [U, U] (row-major, W[out][in])
  u16* cwk = cwq + UU;           // 1M
  u16* cwv = cwk + UU;           // 1M
  u16* cwo = cwv + UU;           // 1M
  u16* q_ws = cwo + UU;          // 4M  [B,H,S,D] (Q pre-scaled by QSCALE2)
  u16* k_ws = q_ws + MU;         // 4M  [B,H,S,D]
  u16* v_ws = k_ws + MU;         // 4M  [B,H,D,S]
  u16* a_ws = v_ws + MU;         // 4M  [B,S,U]
  float* out = (float*)d_out;

  convert_kernel<<<dim3(512, 7), 256, 0, stream>>>(query, key_, value, Wq, Wk, Wv, Wo,
                                                   cq, ck, cv, cwq, cwk, cwv, cwo);
  qkv_gemm<<<dim3(8, 32, 3), 256, 0, stream>>>(cq, ck, cv, cwq, cwk, cwv,
                                               bq, bk, bv, q_ws, k_ws, v_ws);
  flash_attn<<<dim3(1024), 256, 0, stream>>>(q_ws, k_ws, v_ws, a_ws);
  oproj_gemm<<<dim3(8, 32), 256, 0, stream>>>(a_ws, cwo, bo, out);
}

// Round 10
// 227.221 us; speedup vs baseline: 1.2227x; 1.2227x over previous
//
#include <hip/hip_runtime.h>
#include <hip/hip_bf16.h>

// Problem constants
#define U     1024
#define SLEN  2048
#define HEADS 16
#define DK    64
#define MTOT  4096   // B*S
#define MU    (MTOT * U)   // 4M elements
#define UU    (U * U)      // 1M elements

// 1/sqrt(64) * log2(e): folded into Q at the qkv epilogue -> flash softmax
// runs entirely in the exp2 domain with zero per-score scaling.
#define QSCALE2 0.18033688f

typedef unsigned short u16;
typedef short bf16x8 __attribute__((ext_vector_type(8)));
typedef u16 u16x4 __attribute__((ext_vector_type(4)));
typedef float f32x4 __attribute__((ext_vector_type(4)));

__device__ __forceinline__ u16 f2bf(float x) {
  union { float f; unsigned int u; } v; v.f = x;
  unsigned int r = v.u + 0x7fffu + ((v.u >> 16) & 1u);
  return (u16)(r >> 16);
}
// truncating bf16 (1 VALU op); used for P weights only (p>=0, err <= 2^-8 rel)
__device__ __forceinline__ u16 f2bf_rz(float x) {
  return (u16)(__builtin_bit_cast(unsigned int, x) >> 16);
}

#if __has_builtin(__builtin_amdgcn_exp2f)
__device__ __forceinline__ float exp2_fast(float x) { return __builtin_amdgcn_exp2f(x); }
#else
__device__ __forceinline__ float exp2_fast(float x) { return __expf(x * 0.6931472f); }
#endif

// async global->LDS, 16B per lane. LDS dest is wave-uniform base + lane*16.
__device__ __forceinline__ void async16(const u16* g, u16* lds) {
  __builtin_amdgcn_global_load_lds((const __attribute__((address_space(1))) void*)g,
                                   (__attribute__((address_space(3))) void*)lds,
                                   16, 0, 0);
}

// ---- DPP 16-lane sum (VALU-rate); used ONCE at flash epilogue ----
#define DPP_F(x, ctrl) __builtin_bit_cast(float, \
    __builtin_amdgcn_update_dpp(0, __builtin_bit_cast(int, (x)), (ctrl), 0xF, 0xF, true))

__device__ __forceinline__ float rsum16(float x) {
  x += DPP_F(x, 0xB1);
  x += DPP_F(x, 0x4E);
  x += DPP_F(x, 0x141);
  x += DPP_F(x, 0x140);
  return x;
}

// ---------------- fp32 -> bf16 conversion prepass ----------------
__global__ __launch_bounds__(256) void convert_kernel(
    const float* __restrict__ q, const float* __restrict__ k, const float* __restrict__ v,
    const float* __restrict__ wq, const float* __restrict__ wk,
    const float* __restrict__ wv, const float* __restrict__ wo,
    u16* __restrict__ cq, u16* __restrict__ ck, u16* __restrict__ cv,
    u16* __restrict__ cwq, u16* __restrict__ cwk, u16* __restrict__ cwv,
    u16* __restrict__ cwo) {
  const int t = blockIdx.y;
  const float* src = (t == 0) ? q : (t == 1) ? k : (t == 2) ? v
                   : (t == 3) ? wq : (t == 4) ? wk : (t == 5) ? wv : wo;
  u16* dst = (t == 0) ? cq : (t == 1) ? ck : (t == 2) ? cv
           : (t == 3) ? cwq : (t == 4) ? cwk : (t == 5) ? cwv : cwo;
  const int n4 = ((t < 3) ? MU : UU) >> 2;
  const int stride = gridDim.x * blockDim.x;
  for (int i = blockIdx.x * blockDim.x + threadIdx.x; i < n4; i += stride) {
    float4 f = ((const float4*)src)[i];
    u16x4 o = {f2bf(f.x), f2bf(f.y), f2bf(f.z), f2bf(f.w)};
    ((u16x4*)dst)[i] = o;
  }
}

// ---------------- GEMM core: C[128x128] += X[128xK] * W[128xK]^T, K=1024 ----
// R7-PROVEN (44.4 us qkv): BK=32, 3-slot LDS, counted-vmcnt, prefetch depth 2.
//   iter t: vmcnt(4) [retires tile t's 4 loads, issued TWO iters ago] ->
//   s_barrier -> stage tile t+2 into slot (t+2)%3 -> ds_read slot t%3 + 16 MFMA.
// Race-freedom: slot (t+2)%3 held tile t-1, whose last reads precede iter-t's
// barrier in every wave's program order -> safe with ONE barrier/iter.
__device__ __forceinline__ void stage_tile(const u16* __restrict__ src, int kt,
                                           u16* lds, int tid) {
#pragma unroll
  for (int c = 0; c < 2; ++c) {
    int f = c * 256 + tid;               // chunk index 0..511
    int row = f >> 2;
    int qs = f & 3;
    int q = qs ^ ((row >> 1) & 3);       // global 16B-chunk within the row
    const u16* g = src + (size_t)row * U + kt + q * 8;
    u16* l = lds + (size_t)(f & ~63) * 8;  // wave-uniform base (lane bits cleared)
    async16(g, l);
  }
}

__device__ __forceinline__ bf16x8 read_frag(const u16* lds, int lrow, int quad) {
  int qs = quad ^ ((lrow >> 1) & 3);
  return *(const bf16x8*)(lds + (size_t)(lrow * 4 + qs) * 8);
}

__device__ __forceinline__ void gemm128(const u16* __restrict__ X,
                                        const u16* __restrict__ W,
                                        int m0, int n0, int tid,
                                        u16* lds,            // 3 x (4096 A + 4096 B) u16
                                        f32x4 acc[4][4]) {
  const int l = tid & 63, w = tid >> 6;
  const int quad = l >> 4, l15 = l & 15;
  const int wm = w & 1, wn = w >> 1;
  const u16* Xb = X + (size_t)m0 * U;
  const u16* Wb = W + (size_t)n0 * U;

  // prologue: stage K-tiles 0 and 1 (8 loads/thread in flight)
  stage_tile(Xb, 0, lds, tid);
  stage_tile(Wb, 0, lds + 4096, tid);
  stage_tile(Xb, 32, lds + 8192, tid);
  stage_tile(Wb, 32, lds + 8192 + 4096, tid);

  int bufsel = 0;                        // t % 3
  for (int kt = 0; kt < U; kt += 32) {
    if (kt + 32 < U) {
      __builtin_amdgcn_sched_barrier(0);
      asm volatile("s_waitcnt vmcnt(4)" ::: "memory");  // tile t landed (t+1 in flight)
    } else {
      __builtin_amdgcn_sched_barrier(0);
      asm volatile("s_waitcnt vmcnt(0)" ::: "memory");  // last tile: drain
    }
    __builtin_amdgcn_sched_barrier(0);
    __builtin_amdgcn_s_barrier();        // all waves: tile t ready, tile t-1 reads done
    __builtin_amdgcn_sched_barrier(0);

    // stage tile t+2 into slot (t+2)%3 (held tile t-1; freed by this barrier)
    const int s2 = (bufsel >= 1) ? bufsel - 1 : 2;
    if (kt + 64 < U) {
      stage_tile(Xb, kt + 64, lds + s2 * 8192, tid);
      stage_tile(Wb, kt + 64, lds + s2 * 8192 + 4096, tid);
    }
    __builtin_amdgcn_sched_barrier(0);

    const u16* la = lds + bufsel * 8192;
    const u16* lb = la + 4096;
    bf16x8 af[4], bfm[4];
#pragma unroll
    for (int i = 0; i < 4; ++i) af[i] = read_frag(la, wm * 64 + i * 16 + l15, quad);
#pragma unroll
    for (int t = 0; t < 4; ++t) bfm[t] = read_frag(lb, wn * 64 + t * 16 + l15, quad);
#pragma unroll
    for (int i = 0; i < 4; ++i)
#pragma unroll
      for (int t = 0; t < 4; ++t)
        acc[i][t] = __builtin_amdgcn_mfma_f32_16x16x32_bf16(af[i], bfm[t], acc[i][t], 0, 0, 0);
    bufsel = (bufsel == 2) ? 0 : bufsel + 1;
  }
}

// XCD-aware remap for an 8(x) x 32(y) grid: hardware XCD = flat id % 8.
// Map XCD k -> y-panels [4k, 4k+4) x all 8 x-panels, so each X row-panel is
// fetched by exactly ONE XCD's L2 (was 8). Per-XCD working set: 4 X panels
// (1 MB) + full W (2 MB) = 3 MB < 4 MB L2.
__device__ __forceinline__ void xcd_remap(int* m0, int* n0) {
  const int id = blockIdx.x + (blockIdx.y << 3);   // 0..255
  const int k = id & 7, j = id >> 3;               // k = hw XCD
  const int xp = j >> 2;                           // 0..7
  const int yp = (k << 2) | (j & 3);               // 0..31
  *m0 = yp * 128;
  *n0 = xp * 128;
}

// ---------------- QKV projection, fused over z = {q,k,v} ----------------
__global__ __launch_bounds__(256) void qkv_gemm(
    const u16* __restrict__ q_in, const u16* __restrict__ k_in, const u16* __restrict__ v_in,
    const u16* __restrict__ Wq, const u16* __restrict__ Wk, const u16* __restrict__ Wv,
    const float* __restrict__ bq, const float* __restrict__ bk, const float* __restrict__ bv,
    u16* __restrict__ q_ws, u16* __restrict__ k_ws, u16* __restrict__ v_ws) {
  __shared__ __align__(16) u16 lds3[3 * 8192];     // 48 KB -> 3 blocks/CU
  const int z = blockIdx.z;
  const u16* X = (z == 0) ? q_in : (z == 1) ? k_in : v_in;
  const u16* W = (z == 0) ? Wq : (z == 1) ? Wk : Wv;
  const float* bias = (z == 0) ? bq : (z == 1) ? bk : bv;
  int m0, n0;
  xcd_remap(&m0, &n0);
  const int tid = threadIdx.x;
  f32x4 acc[4][4];
#pragma unroll
  for (int i = 0; i < 4; ++i)
#pragma unroll
    for (int t = 0; t < 4; ++t) acc[i][t] = (f32x4){0.f, 0.f, 0.f, 0.f};
  gemm128(X, W, m0, n0, tid, lds3, acc);

  const int l = tid & 63, w = tid >> 6;
  const int quad = l >> 4, l15 = l & 15;
  const int wm = w & 1, wn = w >> 1;
  const float osc = (z == 0) ? QSCALE2 : 1.0f;  // fold softmax scale into Q
#pragma unroll
  for (int t = 0; t < 4; ++t) {
    const int n = n0 + wn * 64 + t * 16 + l15;
    const float bb = bias[n];
    const int h = n >> 6, d = n & 63;
#pragma unroll
    for (int i = 0; i < 4; ++i) {
#pragma unroll
      for (int r = 0; r < 4; ++r) {
        const int m = m0 + wm * 64 + i * 16 + quad * 4 + r;
        const int b = m >> 11, s = m & (SLEN - 1);
        const int bh = b * HEADS + h;
        const u16 ov = f2bf((acc[i][t][r] + bb) * osc);
        if (z == 0)      q_ws[((size_t)bh * SLEN + s) * DK + d] = ov;
        else if (z == 1) k_ws[((size_t)bh * SLEN + s) * DK + d] = ov;
        else             v_ws[((size_t)bh * DK + d) * SLEN + s] = ov;
      }
    }
  }
}

// ---------------- Flash attention (causal, LDS-staged K/V, 64 q-rows/block) ----
// R2-PROVEN config (measured-best flash ~37.6 us): 4 waves x 16 q-rows, QBLK=64,
// 1024 blocks. K/V tiles staged once per block via global_load_lds
// (double-buffered, chunk-XOR swizzled). Block id = (31-qblk)*32 + head:
// longest-first AND same-head blocks cluster on one XCD so KV stays in L2.
// [R5/R6 lesson: frag-reuse redesigns that cut waves/CU lose to latency.]
__global__ __launch_bounds__(256, 4) void flash_attn(const u16* __restrict__ q_ws,
                                                     const u16* __restrict__ k_ws,
                                                     const u16* __restrict__ v_ws,
                                                     u16* __restrict__ a_ws) {
  __shared__ __align__(16) u16 kbuf[2][4096];      // 64 keys x 64 dk, swizzled
  __shared__ __align__(16) u16 vbuf[2][4096];      // 64 d    x 64 keys, swizzled
  __shared__ __align__(16) u16 p_lds[4][16][72];   // per-wave P slab (pad 64->72)
  const int id = blockIdx.x;
  const int bh = id & 31;
  const int qblk = 31 - (id >> 5);     // longest first
  const int tid = threadIdx.x;
  const int w = tid >> 6, l = tid & 63;
  const int quad = l >> 4, l15 = l & 15;
  const int qrow = qblk * 64 + w * 16; // this wave's first q-row
  const int jn = qblk;                 // last (masked) key tile

  const u16* qb = q_ws + (size_t)bh * SLEN * DK;
  const u16* kb = k_ws + (size_t)bh * SLEN * DK;
  const u16* vb = v_ws + (size_t)bh * DK * SLEN;

  // Q A-frags: A[m=lane&15][k=quad*8+j]
  bf16x8 aq0 = *(const bf16x8*)(qb + (size_t)(qrow + l15) * DK + quad * 8);
  bf16x8 aq1 = *(const bf16x8*)(qb + (size_t)(qrow + l15) * DK + 32 + quad * 8);

  f32x4 o[4];
  float l_run[4];
#pragma unroll
  for (int t = 0; t < 4; ++t) o[t] = (f32x4){0.f, 0.f, 0.f, 0.f};
#pragma unroll
  for (int r = 0; r < 4; ++r) l_run[r] = 0.f;

  // ---- cooperative K/V tile staging: 512 chunks each, XOR-swizzled ----
  // chunk f: row=f>>3, slot qs=f&7 holds global col-chunk q = qs ^ (row&7).
  auto stage = [&](int j0, int b) {
#pragma unroll
    for (int c = 0; c < 2; ++c) {
      const int f = c * 256 + tid;
      const int row = f >> 3, qs = f & 7;
      const int q = qs ^ (row & 7);
      u16* kdst = kbuf[b] + (size_t)(f & ~63) * 8;   // wave-uniform base
      u16* vdst = vbuf[b] + (size_t)(f & ~63) * 8;
      async16(kb + (size_t)(j0 + row) * DK + q * 8, kdst);
      async16(vb + (size_t)row * SLEN + j0 + q * 8, vdst);
    }
  };

  stage(0, 0);
  __syncthreads();   // drains vmcnt -> tile 0 ready

  for (int jt = 0; jt <= jn; ++jt) {
    const int buf = jt & 1;
    if (jt < jn) stage((jt + 1) * 64, buf ^ 1);   // async prefetch, no VGPR cost
    const int j0 = jt * 64;
    const int swz = l15 & 7;                      // (t*16+l15)&7 == l15&7

    // ---- S = Q K^T (already exp2-scaled via Q); K-frags from LDS ----
    float sv[4][4];
#pragma unroll
    for (int t = 0; t < 4; ++t) {
      const u16* krow = kbuf[buf] + (size_t)(t * 16 + l15) * 64;
      bf16x8 kf0 = *(const bf16x8*)(krow + ((quad ^ swz) * 8));
      bf16x8 kf1 = *(const bf16x8*)(krow + (((quad + 4) ^ swz) * 8));
      f32x4 acc = (f32x4){0.f, 0.f, 0.f, 0.f};
      acc = __builtin_amdgcn_mfma_f32_16x16x32_bf16(aq0, kf0, acc, 0, 0, 0);
      acc = __builtin_amdgcn_mfma_f32_16x16x32_bf16(aq1, kf1, acc, 0, 0, 0);
#pragma unroll
      for (int r = 0; r < 4; ++r) sv[t][r] = acc[r];
    }
    if (jt == jn) {  // causal mask, block-uniform branch (per-lane predicate)
#pragma unroll
      for (int t = 0; t < 4; ++t) {
        const int col = j0 + t * 16 + l15;
#pragma unroll
        for (int r = 0; r < 4; ++r)
          if (col > qrow + quad * 4 + r) sv[t][r] = -1e30f;  // exp2 -> 0
      }
    }
    // ---- p = exp2(s); unnormalized; per-lane l partial ----
#pragma unroll
    for (int t = 0; t < 4; ++t) {
#pragma unroll
      for (int r = 0; r < 4; ++r) {
        const float p = exp2_fast(sv[t][r]);
        l_run[r] += p;
        p_lds[w][quad * 4 + r][t * 16 + l15] = f2bf_rz(p);  // C-layout -> LDS
      }
    }
    // wave-internal LDS ordering via lgkmcnt (per-wave slab, no barrier)
    bf16x8 pa0 = *(const bf16x8*)&p_lds[w][l15][quad * 8];
    bf16x8 pa1 = *(const bf16x8*)&p_lds[w][l15][32 + quad * 8];
#pragma unroll
    for (int t = 0; t < 4; ++t) {
      const u16* vrow = vbuf[buf] + (size_t)(t * 16 + l15) * 64;
      bf16x8 vf0 = *(const bf16x8*)(vrow + ((quad ^ swz) * 8));
      bf16x8 vf1 = *(const bf16x8*)(vrow + (((quad + 4) ^ swz) * 8));
      o[t] = __builtin_amdgcn_mfma_f32_16x16x32_bf16(pa0, vf0, o[t], 0, 0, 0);
      o[t] = __builtin_amdgcn_mfma_f32_16x16x32_bf16(pa1, vf1, o[t], 0, 0, 0);
    }
    __syncthreads();  // all waves done with buf; prefetch into buf^1 drained
  }
  // ---- epilogue: each wave normalizes & stores its own 16 rows ----
  const int b = bh >> 4, h = bh & 15;
  float inv[4];
#pragma unroll
  for (int r = 0; r < 4; ++r) inv[r] = 1.f / rsum16(l_run[r]);
#pragma unroll
  for (int r = 0; r < 4; ++r) {
    const int s = qrow + quad * 4 + r;
    u16* orow = a_ws + ((size_t)b * SLEN + s) * U + h * DK;
#pragma unroll
    for (int t = 0; t < 4; ++t)
      orow[t * 16 + l15] = f2bf(o[t][r] * inv[r]);
  }
}

// ---------------- output projection: 64x128 tile, 512 blocks (2/CU) ----------------
// R10: oproj was the last 1-block/CU kernel -- same barrier-lockstep critical
// path as qkv but with ZERO inter-block overlap (the R3 disease). Halving the
// M-tile doubles the grid to 512 (2 blocks/CU resident; LDS 36 KB allows 4).
// Same R7-proven 3-slot depth-2 counted-vmcnt schedule; 3 loads/thread/tile
// (A 1 + B 2) -> steady-state wait is vmcnt(3). 4 waves split N: wave tile
// 64x32, acc[4][2], 8 MFMA per 6 ds_read_b128.
__global__ __launch_bounds__(256) void oproj_gemm(const u16* __restrict__ A,
                                                  const u16* __restrict__ Wo,
                                                  const float* __restrict__ bo,
                                                  float* __restrict__ out) {
  __shared__ __align__(16) u16 lds3[3 * 6144];   // 3 x (A 2048 + B 4096) u16 = 36 KB
  // XCD map: XCD k owns m-panels [8k,8k+8) x all 8 n-panels.
  // Per-XCD working set: A 8x64 rows (1 MB) + full Wo (2 MB) = 3 MB < 4 MB L2.
  const int id = blockIdx.x;
  const int k8 = id & 7, j = id >> 3;            // j 0..63
  const int m0 = (k8 * 8 + (j >> 3)) * 64;       // mp 0..63
  const int n0 = (j & 7) * 128;                  // np 0..7
  const int tid = threadIdx.x;
  const int l = tid & 63, w = tid >> 6;
  const int quad = l >> 4, l15 = l & 15;
  const int wn = w;                              // 4 waves x 32 N-cols
  const u16* Ab = A + (size_t)m0 * U;
  const u16* Wb = Wo + (size_t)n0 * U;

  // A tile 64x32 = 256 chunks (1/thread); B tile 128x32 = 512 chunks (2/thread)
  auto stage_a = [&](int kt, u16* slot) {
    const int f = tid;                           // 0..255
    const int row = f >> 2, qs = f & 3;
    const int q = qs ^ ((row >> 1) & 3);
    async16(Ab + (size_t)row * U + kt + q * 8, slot + (size_t)(f & ~63) * 8);
  };
  auto stage_b = [&](int kt, u16* slot) {
#pragma unroll
    for (int c = 0; c < 2; ++c) {
      const int f = c * 256 + tid;               // 0..511
      const int row = f >> 2, qs = f & 3;
      const int q = qs ^ ((row >> 1) & 3);
      async16(Wb + (size_t)row * U + kt + q * 8, slot + (size_t)(f & ~63) * 8);
    }
  };

  f32x4 acc[4][2];
#pragma unroll
  for (int i = 0; i < 4; ++i)
#pragma unroll
    for (int t = 0; t < 2; ++t) acc[i][t] = (f32x4){0.f, 0.f, 0.f, 0.f};

  // prologue: stage tiles 0,1 (6 loads/thread in flight)
  stage_a(0, lds3);            stage_b(0, lds3 + 2048);
  stage_a(32, lds3 + 6144);    stage_b(32, lds3 + 6144 + 2048);

  int bufsel = 0;                                // t % 3
  for (int kt = 0; kt < U; kt += 32) {
    if (kt + 32 < U) {
      __builtin_amdgcn_sched_barrier(0);
      asm volatile("s_waitcnt vmcnt(3)" ::: "memory");  // tile t landed (t+1 in flight)
    } else {
      __builtin_amdgcn_sched_barrier(0);
      asm volatile("s_waitcnt vmcnt(0)" ::: "memory");  // last tile: drain
    }
    __builtin_amdgcn_sched_barrier(0);
    __builtin_amdgcn_s_barrier();                // tile t ready; t-1 reads done
    __builtin_amdgcn_sched_barrier(0);

    const int s2 = (bufsel >= 1) ? bufsel - 1 : 2;  // slot (t+2)%3, freed by barrier
    if (kt + 64 < U) {
      stage_a(kt + 64, lds3 + s2 * 6144);
      stage_b(kt + 64, lds3 + s2 * 6144 + 2048);
    }
    __builtin_amdgcn_sched_barrier(0);

    const u16* la = lds3 + bufsel * 6144;        // A: 64 rows
    const u16* lb = la + 2048;                   // B: 128 rows
    bf16x8 af[4], bfm[2];
#pragma unroll
    for (int i = 0; i < 4; ++i) af[i] = read_frag(la, i * 16 + l15, quad);
#pragma unroll
    for (int t = 0; t < 2; ++t) bfm[t] = read_frag(lb, wn * 32 + t * 16 + l15, quad);
#pragma unroll
    for (int i = 0; i < 4; ++i)
#pragma unroll
      for (int t = 0; t < 2; ++t)
        acc[i][t] = __builtin_amdgcn_mfma_f32_16x16x32_bf16(af[i], bfm[t], acc[i][t], 0, 0, 0);
    bufsel = (bufsel == 2) ? 0 : bufsel + 1;
  }

#pragma unroll
  for (int t = 0; t < 2; ++t) {
    const int n = n0 + wn * 32 + t * 16 + l15;
    const float bb = bo[n];
#pragma unroll
    for (int i = 0; i < 4; ++i) {
#pragma unroll
      for (int r = 0; r < 4; ++r) {
        const int m = m0 + i * 16 + quad * 4 + r;
        out[(size_t)m * U + n] = acc[i][t][r] + bb;
      }
    }
  }
}

extern "C" void kernel_launch(void* const* d_in, const int* in_sizes, int n_in,
                              void* d_out, int out_size, void* d_ws, size_t ws_size,
                              hipStream_t stream) {
  (void)in_sizes; (void)n_in; (void)out_size; (void)ws_size;
  const float* query = (const float*)d_in[0];
  const float* key_  = (const float*)d_in[1];
  const float* value = (const float*)d_in[2];
  // d_in[3] = mask (tril causal; hardcoded in flash kernel)
  const float* Wq = (const float*)d_in[4];
  const float* bq = (const float*)d_in[5];
  const float* Wk = (const float*)d_in[6];
  const float* bk = (const float*)d_in[7];
  const float* Wv = (const float*)d_in[8];
  const float* bv = (const float*)d_in[9];
  const float* Wo = (const float*)d_in[10];
  const float* bo = (const float*)d_in[11];

  u16* ws = (u16*)d_ws;
  u16* cq  = ws;                 // 4M bf16 [B*S, U]
  u16* ck  = cq + MU;            // 4M
  u16* cv  = ck + MU;            // 4M
  u16* cwq = cv + MU;            // 1M bf16 [U, U] (row-major, W[out][in])
  u16* cwk = cwq + UU;           // 1M
  u16* cwv = cwk + UU;           // 1M
  u16* cwo = cwv + UU;           // 1M
  u16* q_ws = cwo + UU;          // 4M  [B,H,S,D] (Q pre-scaled by QSCALE2)
  u16* k_ws = q_ws + MU;         // 4M  [B,H,S,D]
  u16* v_ws = k_ws + MU;         // 4M  [B,H,D,S]
  u16* a_ws = v_ws + MU;         // 4M  [B,S,U]
  float* out = (float*)d_out;

  convert_kernel<<<dim3(512, 7), 256, 0, stream>>>(query, key_, value, Wq, Wk, Wv, Wo,
                                                   cq, ck, cv, cwq, cwk, cwv, cwo);
  qkv_gemm<<<dim3(8, 32, 3), 256, 0, stream>>>(cq, ck, cv, cwq, cwk, cwv,
                                               bq, bk, bv, q_ws, k_ws, v_ws);
  flash_attn<<<dim3(1024), 256, 0, stream>>>(q_ws, k_ws, v_ws, a_ws);
  oproj_gemm<<<dim3(512), 256, 0, stream>>>(a_ws, cwo, bo, out);
}